// Round 11
// baseline (134.105 us; speedup 1.0000x reference)
//
#include <hip/hip_runtime.h>

#define BATCH 16384
#define DIM   512
#define UNITS 1024
// GAMMA = 0.5 folded into epilogue: out = exp(cross - 0.5*xsq - 0.5*musq)

typedef float v16f __attribute__((ext_vector_type(16)));

#define BPITCH 33
#define MFMA_F8(a, b, c) __builtin_amdgcn_mfma_f32_32x32x16_fp8_fp8((a), (b), (c), 0, 0, 0)

static __device__ __forceinline__ int2 cvt8(const float4 f0, const float4 f1) {
    int lo = __builtin_amdgcn_cvt_pk_fp8_f32(f0.x, f0.y, 0, false);
    lo     = __builtin_amdgcn_cvt_pk_fp8_f32(f0.z, f0.w, lo, true);
    int hi = __builtin_amdgcn_cvt_pk_fp8_f32(f1.x, f1.y, 0, false);
    hi     = __builtin_amdgcn_cvt_pk_fp8_f32(f1.z, f1.w, hi, true);
    return make_int2(lo, hi);
}
static __device__ __forceinline__ float dot8(const float4 f0, const float4 f1) {
    return f0.x * f0.x + f0.y * f0.y + f0.z * f0.z + f0.w * f0.w
         + f1.x * f1.x + f1.y * f1.y + f1.z * f1.z + f1.w * f1.w;
}

// prep-B (R0's proven B-path, unchanged): 32 blocks x 256 threads.
// B8f: byte ((ng*32 + kw)*64 + lane)*8 — lane l holds
//   B[kw*16 + (l>>5)*8 + 0..7][ng*32 + (l&31)].  musq on fp32 values.
__global__ __launch_bounds__(256)
void prep_b_kernel(const float* __restrict__ mu, unsigned char* __restrict__ B8f,
                   float* __restrict__ musq) {
    __shared__ __attribute__((aligned(16))) char smem[512 * BPITCH * 4 + 1024];
    float* lds = (float*)smem;                       // [512][BPITCH]
    float* red = (float*)(smem + 512 * BPITCH * 4);  // [32][8]
    const int t  = threadIdx.x;
    const int l  = t & 63, w = t >> 6;
    const int ln = l & 31, h = l >> 5;
    const int nb = blockIdx.x;
    const int n0 = nb * 32;
    const int col = t & 31, kg = t >> 5;
    float s = 0.f;
    for (int i = 0; i < 64; i++) {
        const int k = i * 8 + kg;
        float v = mu[(size_t)k * UNITS + n0 + col];
        s += v * v;
        lds[k * BPITCH + col] = v;
    }
    red[col * 8 + kg] = s;
    __syncthreads();
    if (t < 32) {
        float a = 0.f;
#pragma unroll
        for (int i = 0; i < 8; i++) a += red[t * 8 + i];
        musq[n0 + t] = a;
    }
#pragma unroll
    for (int j = 0; j < 8; j++) {
        const int kw = w * 8 + j;
        const float* p = lds + (kw * 16 + h * 8) * BPITCH + ln;
        float f[8];
#pragma unroll
        for (int i = 0; i < 8; i++) f[i] = p[i * BPITCH];
        *(int2*)(B8f + (((size_t)nb * 32 + kw) * 64 + l) * 8) =
            cvt8(make_float4(f[0], f[1], f[2], f[3]),
                 make_float4(f[4], f[5], f[6], f[7]));
    }
}

// Main RBF kernel v4: R10's shell (256 blocks x 1024 threads, 16 waves,
// 1 block/CU, block-private 64 A-rows in LDS, wave tile 64M x 64N as two
// 64M x 32N passes) with ONE change: each pass's 32 B-loads are hoisted
// into registers BEFORE the MFMA loop (long br[32], fully unrolled ->
// static VGPR indexing). The K-loop is now pure {2 LDS-A + 2 MFMA} with no
// global latency inside; pass-1's B-burst issues before pass-0's epilogue
// so its latency hides under the exp/store VALU work. VGPR ~112 <= 128
// (4 waves/SIMD). Staging, prep-B, layouts, epilogue: identical to R10.
__global__ __launch_bounds__(1024, 4)
void rbf_main_kernel(const float* __restrict__ in,
                     const unsigned char* __restrict__ B8f,
                     const float* __restrict__ musq,
                     float* __restrict__ out) {
    // LDS: stage 66048 | Afrag 32768 | red 8448 | xsq_l 256  = 107520 B
    __shared__ __attribute__((aligned(16))) unsigned char smem[107520];
    float* stage = (float*)smem;                         // [32][516] fp32
    unsigned char* Afrag = smem + 66048;                 // [2][32 kw][64 l][8]
    float* red   = (float*)(smem + 98816);               // [64][33]
    float* xsq_l = (float*)(smem + 107264);              // [64]

    const int t  = threadIdx.x;
    const int l  = t & 63;
    const int w  = t >> 6;          // wave 0..15 = 64-col group
    const int ln = l & 31;
    const int h  = l >> 5;
    const int m0 = blockIdx.x * 64; // this block's 64 A-rows

    // ---- Stage + convert two 32-row chunks (identical to R10) ----
#pragma unroll
    for (int rc = 0; rc < 2; rc++) {
        const float4* src = (const float4*)(in + (size_t)(m0 + rc * 32) * DIM);
        float4* s4 = (float4*)stage;
#pragma unroll
        for (int i = 0; i < 4; i++) {
            const int f = i * 1024 + t;                  // float4 id 0..4095
            s4[(f >> 7) * 129 + (f & 127)] = src[f];
        }
        __syncthreads();
        // convert: thread covers (row ln, k-half h) x kw = {w*2, w*2+1}
        float s = 0.f;
#pragma unroll
        for (int j = 0; j < 2; j++) {
            const int kw = w * 2 + j;
            const float* p = stage + ln * 516 + kw * 16 + h * 8;
            float4 f0 = *(const float4*)p;
            float4 f1 = *(const float4*)(p + 4);
            s += dot8(f0, f1);
            *(int2*)(Afrag + (((rc * 32 + kw) * 64) + h * 32 + ln) * 8) =
                cvt8(f0, f1);
        }
        red[(rc * 32 + ln) * 33 + w * 2 + h] = s;
        __syncthreads();
    }
    if (t < 64) {                   // xsq for all 64 rows, stays in LDS
        float a = 0.f;
#pragma unroll
        for (int i = 0; i < 32; i++) a += red[t * 33 + i];
        xsq_l[t] = -0.5f * a;
    }
    __syncthreads();                // last barrier; waves free-run from here

    // ---- Per-wave GEMM: rows [m0,+64) x cols [w*64,+64), 2 N-passes ----
    const long* Af0 = (const long*)Afrag;                // row chunk 0
    const long* Af1 = (const long*)(Afrag + 16384);      // row chunk 1
    const long* Bg  = (const long*)B8f + (size_t)(w * 2) * 2048 + l;

    // Pass 0: preload all 32 B-fragments into registers, then pure MFMA loop.
    long br0[32];
#pragma unroll
    for (int k = 0; k < 32; k++) br0[k] = Bg[k * 64];

    v16f acc0 = (v16f)0.f, acc1 = (v16f)0.f;
#pragma unroll
    for (int k = 0; k < 32; k++) {
        long a0 = Af0[k * 64 + l];
        long a1 = Af1[k * 64 + l];
        acc0 = MFMA_F8(a0, br0[k], acc0);                // rows m0..m0+31
        acc1 = MFMA_F8(a1, br0[k], acc1);                // rows m0+32..m0+63
    }

    // Pass 1 B-burst issued BEFORE pass-0 epilogue (latency hides under it).
    long br1[32];
#pragma unroll
    for (int k = 0; k < 32; k++) br1[k] = Bg[2048 + k * 64];

    // ---- Pass-0 epilogue. C/D layout: col=l&31, row=(r&3)+8*(r>>2)+4*h ----
    {
        const int nc0 = w * 64;
        const float mb = -0.5f * musq[nc0 + ln];
        float* obase = out + nc0 + ln;
#pragma unroll
        for (int r = 0; r < 16; r++) {
            const int rl = (r & 3) + 8 * (r >> 2) + 4 * h;
            __builtin_nontemporal_store(
                __expf(acc0[r] + xsq_l[rl] + mb),
                obase + (size_t)(m0 + rl) * UNITS);
            __builtin_nontemporal_store(
                __expf(acc1[r] + xsq_l[32 + rl] + mb),
                obase + (size_t)(m0 + 32 + rl) * UNITS);
        }
    }

    // ---- Pass 1: pure MFMA loop on preloaded B ----
    v16f acc2 = (v16f)0.f, acc3 = (v16f)0.f;
#pragma unroll
    for (int k = 0; k < 32; k++) {
        long a0 = Af0[k * 64 + l];
        long a1 = Af1[k * 64 + l];
        acc2 = MFMA_F8(a0, br1[k], acc2);
        acc3 = MFMA_F8(a1, br1[k], acc3);
    }

    // ---- Pass-1 epilogue ----
    {
        const int nc0 = w * 64 + 32;
        const float mb = -0.5f * musq[nc0 + ln];
        float* obase = out + nc0 + ln;
#pragma unroll
        for (int r = 0; r < 16; r++) {
            const int rl = (r & 3) + 8 * (r >> 2) + 4 * h;
            __builtin_nontemporal_store(
                __expf(acc2[r] + xsq_l[rl] + mb),
                obase + (size_t)(m0 + rl) * UNITS);
            __builtin_nontemporal_store(
                __expf(acc3[r] + xsq_l[32 + rl] + mb),
                obase + (size_t)(m0 + 32 + rl) * UNITS);
        }
    }
}

extern "C" void kernel_launch(void* const* d_in, const int* in_sizes, int n_in,
                              void* d_out, int out_size, void* d_ws, size_t ws_size,
                              hipStream_t stream) {
    const float* inputs = (const float*)d_in[0];   // [16384, 512] fp32
    const float* mu     = (const float*)d_in[1];   // [512, 1024] fp32
    float* out = (float*)d_out;                    // [16384, 1024] fp32

    char* ws = (char*)d_ws;
    unsigned char* B8f = (unsigned char*)ws;                 // 512 KiB
    float* musq = (float*)(ws + (size_t)UNITS * DIM);        // 4 KiB

    prep_b_kernel<<<32, 256, 0, stream>>>(mu, B8f, musq);
    rbf_main_kernel<<<256, 1024, 0, stream>>>(inputs, B8f, musq, out);
}

// Round 12
// 114.511 us; speedup vs baseline: 1.1711x; 1.1711x over previous
//
#include <hip/hip_runtime.h>

#define BATCH 16384
#define DIM   512
#define UNITS 1024
// GAMMA = 0.5 folded into epilogue: out = exp(cross - 0.5*xsq - 0.5*musq)

typedef float v16f __attribute__((ext_vector_type(16)));

#define BPITCH 33
#define MFMA_F8(a, b, c) __builtin_amdgcn_mfma_f32_32x32x16_fp8_fp8((a), (b), (c), 0, 0, 0)

static __device__ __forceinline__ int2 cvt8(const float4 f0, const float4 f1) {
    int lo = __builtin_amdgcn_cvt_pk_fp8_f32(f0.x, f0.y, 0, false);
    lo     = __builtin_amdgcn_cvt_pk_fp8_f32(f0.z, f0.w, lo, true);
    int hi = __builtin_amdgcn_cvt_pk_fp8_f32(f1.x, f1.y, 0, false);
    hi     = __builtin_amdgcn_cvt_pk_fp8_f32(f1.z, f1.w, hi, true);
    return make_int2(lo, hi);
}
static __device__ __forceinline__ float dot8(const float4 f0, const float4 f1) {
    return f0.x * f0.x + f0.y * f0.y + f0.z * f0.z + f0.w * f0.w
         + f1.x * f1.x + f1.y * f1.y + f1.z * f1.z + f1.w * f1.w;
}

// prep-B (R0's proven B-path, unchanged): 32 blocks x 256 threads.
// B8f: byte ((ng*32 + kw)*64 + lane)*8 — lane l holds
//   B[kw*16 + (l>>5)*8 + 0..7][ng*32 + (l&31)].  musq on fp32 values.
__global__ __launch_bounds__(256)
void prep_b_kernel(const float* __restrict__ mu, unsigned char* __restrict__ B8f,
                   float* __restrict__ musq) {
    __shared__ __attribute__((aligned(16))) char smem[512 * BPITCH * 4 + 1024];
    float* lds = (float*)smem;                       // [512][BPITCH]
    float* red = (float*)(smem + 512 * BPITCH * 4);  // [32][8]
    const int t  = threadIdx.x;
    const int l  = t & 63, w = t >> 6;
    const int ln = l & 31, h = l >> 5;
    const int nb = blockIdx.x;
    const int n0 = nb * 32;
    const int col = t & 31, kg = t >> 5;
    float s = 0.f;
    for (int i = 0; i < 64; i++) {
        const int k = i * 8 + kg;
        float v = mu[(size_t)k * UNITS + n0 + col];
        s += v * v;
        lds[k * BPITCH + col] = v;
    }
    red[col * 8 + kg] = s;
    __syncthreads();
    if (t < 32) {
        float a = 0.f;
#pragma unroll
        for (int i = 0; i < 8; i++) a += red[t * 8 + i];
        musq[n0 + t] = a;
    }
#pragma unroll
    for (int j = 0; j < 8; j++) {
        const int kw = w * 8 + j;
        const float* p = lds + (kw * 16 + h * 8) * BPITCH + ln;
        float f[8];
#pragma unroll
        for (int i = 0; i < 8; i++) f[i] = p[i * BPITCH];
        *(int2*)(B8f + (((size_t)nb * 32 + kw) * 64 + l) * 8) =
            cvt8(make_float4(f[0], f[1], f[2], f[3]),
                 make_float4(f[4], f[5], f[6], f[7]));
    }
}

// Main RBF kernel v5: R10's shell + K-loop/epilogue VERBATIM (the validated
// best), with the A-staging replaced by DIRECT fragment-order global loads:
// thread (w, ln, h) loads A[m0+rc*32+ln][(w*2+j)*16 + h*8 ..+8] (two float4s)
// for rc,j in {0,1}^2 — wave w's two j-loads exactly cover one 128-B line
// per row (zero overfetch, no cross-wave sharing). This deletes the fp32
// stage buffer, the LDS round-trip and two barriers; staging is an 8-load
// burst + cvt + one barrier. LDS 107.5 -> 41.5 KB. xsq partials unchanged
// (dot8 on original fp32). NOT R3's pattern: one-shot burst, not in-loop.
__global__ __launch_bounds__(1024, 4)
void rbf_main_kernel(const float* __restrict__ in,
                     const unsigned char* __restrict__ B8f,
                     const float* __restrict__ musq,
                     float* __restrict__ out) {
    // LDS: Afrag 32768 | red 8448 | xsq_l 256  = 41472 B
    __shared__ __attribute__((aligned(16))) unsigned char smem[41472];
    unsigned char* Afrag = smem;                         // [2][32 kw][64 l][8]
    float* red   = (float*)(smem + 32768);               // [64][33]
    float* xsq_l = (float*)(smem + 41216);               // [64]

    const int t  = threadIdx.x;
    const int l  = t & 63;
    const int w  = t >> 6;          // wave 0..15 = 64-col group
    const int ln = l & 31;
    const int h  = l >> 5;
    const int m0 = blockIdx.x * 64; // this block's 64 A-rows

    // ---- Direct fragment-order A staging: 8 float4 burst loads ----
    {
        float4 fa[4], fb[4];
#pragma unroll
        for (int rc = 0; rc < 2; rc++)
#pragma unroll
            for (int j = 0; j < 2; j++) {
                const float* p = in + (size_t)(m0 + rc * 32 + ln) * DIM
                               + (w * 2 + j) * 16 + h * 8;
                fa[rc * 2 + j] = *(const float4*)p;
                fb[rc * 2 + j] = *(const float4*)(p + 4);
            }
#pragma unroll
        for (int rc = 0; rc < 2; rc++) {
            float s = 0.f;
#pragma unroll
            for (int j = 0; j < 2; j++) {
                const int kw = w * 2 + j;
                s += dot8(fa[rc * 2 + j], fb[rc * 2 + j]);
                *(int2*)(Afrag + (((rc * 32 + kw) * 64) + h * 32 + ln) * 8) =
                    cvt8(fa[rc * 2 + j], fb[rc * 2 + j]);
            }
            red[(rc * 32 + ln) * 33 + w * 2 + h] = s;
        }
    }
    __syncthreads();
    if (t < 64) {                   // xsq for all 64 rows, stays in LDS
        float a = 0.f;
#pragma unroll
        for (int i = 0; i < 32; i++) a += red[t * 33 + i];
        xsq_l[t] = -0.5f * a;
    }
    __syncthreads();                // last barrier; waves free-run from here

    // ---- Per-wave GEMM (R10 verbatim): rows [m0,+64) x cols [w*64,+64) ----
    const long* Af0 = (const long*)Afrag;                // row chunk 0
    const long* Af1 = (const long*)(Afrag + 16384);      // row chunk 1
    const long* Bg  = (const long*)B8f + (size_t)(w * 2) * 2048 + l;

#pragma unroll
    for (int g2 = 0; g2 < 2; g2++) {                     // two 32-col passes
        const long* B0 = Bg + (size_t)g2 * 2048;

        v16f acc0 = (v16f)0.f, acc1 = (v16f)0.f;
#pragma unroll 8
        for (int kw = 0; kw < 32; kw++) {
            long a0 = Af0[kw * 64 + l];
            long a1 = Af1[kw * 64 + l];
            long b  = B0[kw * 64];
            acc0 = MFMA_F8(a0, b, acc0);                 // rows m0..m0+31
            acc1 = MFMA_F8(a1, b, acc1);                 // rows m0+32..m0+63
        }

        // Epilogue. C/D layout: col = l&31, row = (r&3) + 8*(r>>2) + 4*h.
        const int nc0 = w * 64 + g2 * 32;
        const float mb = -0.5f * musq[nc0 + ln];
        float* obase = out + nc0 + ln;
#pragma unroll
        for (int r = 0; r < 16; r++) {
            const int rl = (r & 3) + 8 * (r >> 2) + 4 * h;
            const float xb0 = xsq_l[rl];                 // LDS broadcast
            const float xb1 = xsq_l[32 + rl];
            __builtin_nontemporal_store(
                __expf(acc0[r] + xb0 + mb), obase + (size_t)(m0 + rl) * UNITS);
            __builtin_nontemporal_store(
                __expf(acc1[r] + xb1 + mb), obase + (size_t)(m0 + 32 + rl) * UNITS);
        }
    }
}

extern "C" void kernel_launch(void* const* d_in, const int* in_sizes, int n_in,
                              void* d_out, int out_size, void* d_ws, size_t ws_size,
                              hipStream_t stream) {
    const float* inputs = (const float*)d_in[0];   // [16384, 512] fp32
    const float* mu     = (const float*)d_in[1];   // [512, 1024] fp32
    float* out = (float*)d_out;                    // [16384, 1024] fp32

    char* ws = (char*)d_ws;
    unsigned char* B8f = (unsigned char*)ws;                 // 512 KiB
    float* musq = (float*)(ws + (size_t)UNITS * DIM);        // 4 KiB

    prep_b_kernel<<<32, 256, 0, stream>>>(mu, B8f, musq);
    rbf_main_kernel<<<256, 1024, 0, stream>>>(inputs, B8f, musq, out);
}

// Round 13
// 112.603 us; speedup vs baseline: 1.1910x; 1.0170x over previous
//
#include <hip/hip_runtime.h>

#define BATCH 16384
#define DIM   512
#define UNITS 1024
// GAMMA = 0.5 folded into epilogue: out = exp(cross - 0.5*xsq - 0.5*musq)

typedef float v16f __attribute__((ext_vector_type(16)));

#define BPITCH 33
#define MFMA_F8(a, b, c) __builtin_amdgcn_mfma_f32_32x32x16_fp8_fp8((a), (b), (c), 0, 0, 0)

static __device__ __forceinline__ int2 cvt8(const float4 f0, const float4 f1) {
    int lo = __builtin_amdgcn_cvt_pk_fp8_f32(f0.x, f0.y, 0, false);
    lo     = __builtin_amdgcn_cvt_pk_fp8_f32(f0.z, f0.w, lo, true);
    int hi = __builtin_amdgcn_cvt_pk_fp8_f32(f1.x, f1.y, 0, false);
    hi     = __builtin_amdgcn_cvt_pk_fp8_f32(f1.z, f1.w, hi, true);
    return make_int2(lo, hi);
}
static __device__ __forceinline__ float dot8(const float4 f0, const float4 f1) {
    return f0.x * f0.x + f0.y * f0.y + f0.z * f0.z + f0.w * f0.w
         + f1.x * f1.x + f1.y * f1.y + f1.z * f1.z + f1.w * f1.w;
}

// prep-B (R0's proven B-path, unchanged): 32 blocks x 256 threads.
// B8f: byte ((ng*32 + kw)*64 + lane)*8 — lane l holds
//   B[kw*16 + (l>>5)*8 + 0..7][ng*32 + (l&31)].  musq on fp32 values.
__global__ __launch_bounds__(256)
void prep_b_kernel(const float* __restrict__ mu, unsigned char* __restrict__ B8f,
                   float* __restrict__ musq) {
    __shared__ __attribute__((aligned(16))) char smem[512 * BPITCH * 4 + 1024];
    float* lds = (float*)smem;                       // [512][BPITCH]
    float* red = (float*)(smem + 512 * BPITCH * 4);  // [32][8]
    const int t  = threadIdx.x;
    const int l  = t & 63, w = t >> 6;
    const int ln = l & 31, h = l >> 5;
    const int nb = blockIdx.x;
    const int n0 = nb * 32;
    const int col = t & 31, kg = t >> 5;
    float s = 0.f;
    for (int i = 0; i < 64; i++) {
        const int k = i * 8 + kg;
        float v = mu[(size_t)k * UNITS + n0 + col];
        s += v * v;
        lds[k * BPITCH + col] = v;
    }
    red[col * 8 + kg] = s;
    __syncthreads();
    if (t < 32) {
        float a = 0.f;
#pragma unroll
        for (int i = 0; i < 8; i++) a += red[t * 8 + i];
        musq[n0 + t] = a;
    }
#pragma unroll
    for (int j = 0; j < 8; j++) {
        const int kw = w * 8 + j;
        const float* p = lds + (kw * 16 + h * 8) * BPITCH + ln;
        float f[8];
#pragma unroll
        for (int i = 0; i < 8; i++) f[i] = p[i * BPITCH];
        *(int2*)(B8f + (((size_t)nb * 32 + kw) * 64 + l) * 8) =
            cvt8(make_float4(f[0], f[1], f[2], f[3]),
                 make_float4(f[4], f[5], f[6], f[7]));
    }
}

// Main RBF kernel v6: R10 (validated best) + ONE change: pass-0's epilogue
// is software-pipelined into pass-1's K-loop (one r-iter per 2 kw-iters,
// fully unrolled -> static acc0[r] indexing). Stores+exp issue in pass-1's
// MFMA shadow WITHIN each wave instead of relying only on inter-wave drift.
// 4 accs live (~100 VGPR) < 128 cap at 4 waves/SIMD -> no spill.
// Staging (coalesced load -> LDS[32][516] transpose -> cvt -> Afrag),
// prep-B, layouts, grid: byte-identical to R10.
__global__ __launch_bounds__(1024, 4)
void rbf_main_kernel(const float* __restrict__ in,
                     const unsigned char* __restrict__ B8f,
                     const float* __restrict__ musq,
                     float* __restrict__ out) {
    // LDS: stage 66048 | Afrag 32768 | red 8448 | xsq_l 256  = 107520 B
    __shared__ __attribute__((aligned(16))) unsigned char smem[107520];
    float* stage = (float*)smem;                         // [32][516] fp32
    unsigned char* Afrag = smem + 66048;                 // [2][32 kw][64 l][8]
    float* red   = (float*)(smem + 98816);               // [64][33]
    float* xsq_l = (float*)(smem + 107264);              // [64]

    const int t  = threadIdx.x;
    const int l  = t & 63;
    const int w  = t >> 6;          // wave 0..15 = 64-col group
    const int ln = l & 31;
    const int h  = l >> 5;
    const int m0 = blockIdx.x * 64; // this block's 64 A-rows

    // ---- Stage + convert two 32-row chunks (identical to R10) ----
#pragma unroll
    for (int rc = 0; rc < 2; rc++) {
        const float4* src = (const float4*)(in + (size_t)(m0 + rc * 32) * DIM);
        float4* s4 = (float4*)stage;
#pragma unroll
        for (int i = 0; i < 4; i++) {
            const int f = i * 1024 + t;                  // float4 id 0..4095
            s4[(f >> 7) * 129 + (f & 127)] = src[f];
        }
        __syncthreads();
        // convert: thread covers (row ln, k-half h) x kw = {w*2, w*2+1}
        float s = 0.f;
#pragma unroll
        for (int j = 0; j < 2; j++) {
            const int kw = w * 2 + j;
            const float* p = stage + ln * 516 + kw * 16 + h * 8;
            float4 f0 = *(const float4*)p;
            float4 f1 = *(const float4*)(p + 4);
            s += dot8(f0, f1);
            *(int2*)(Afrag + (((rc * 32 + kw) * 64) + h * 32 + ln) * 8) =
                cvt8(f0, f1);
        }
        red[(rc * 32 + ln) * 33 + w * 2 + h] = s;
        __syncthreads();
    }
    if (t < 64) {                   // xsq for all 64 rows, stays in LDS
        float a = 0.f;
#pragma unroll
        for (int i = 0; i < 32; i++) a += red[t * 33 + i];
        xsq_l[t] = -0.5f * a;
    }
    __syncthreads();                // last barrier; waves free-run from here

    // ---- Per-wave GEMM: rows [m0,+64) x cols [w*64,+64) ----
    const long* Af0 = (const long*)Afrag;                // row chunk 0
    const long* Af1 = (const long*)(Afrag + 16384);      // row chunk 1
    const long* Bg  = (const long*)B8f + (size_t)(w * 2) * 2048 + l;

    // Pass 0 K-loop (R10 verbatim, cols [w*64, +32)).
    v16f acc0 = (v16f)0.f, acc1 = (v16f)0.f;
#pragma unroll 8
    for (int kw = 0; kw < 32; kw++) {
        long a0 = Af0[kw * 64 + l];
        long a1 = Af1[kw * 64 + l];
        long b  = Bg[kw * 64];
        acc0 = MFMA_F8(a0, b, acc0);                     // rows m0..m0+31
        acc1 = MFMA_F8(a1, b, acc1);                     // rows m0+32..m0+63
    }

    // Pass 1 K-loop (cols [w*64+32, +32)) with pass-0 epilogue interleaved:
    // one r-iter (2 exp + 2 NT stores) per 2 kw-iters, fully unrolled.
    // C/D layout: col = l&31, row = (r&3) + 8*(r>>2) + 4*h.
    const float mbA = -0.5f * musq[w * 64 + ln];
    const float mbB = -0.5f * musq[w * 64 + 32 + ln];
    float* obA = out + w * 64 + ln;
    float* obB = out + w * 64 + 32 + ln;

    v16f acc2 = (v16f)0.f, acc3 = (v16f)0.f;
#pragma unroll
    for (int kw = 0; kw < 32; kw++) {
        long a0 = Af0[kw * 64 + l];
        long a1 = Af1[kw * 64 + l];
        long b  = Bg[2048 + kw * 64];
        acc2 = MFMA_F8(a0, b, acc2);
        acc3 = MFMA_F8(a1, b, acc3);
        if ((kw & 1) == 0) {                             // drain pass 0
            const int r  = kw >> 1;                      // 0..15 (constant)
            const int rl = (r & 3) + 8 * (r >> 2) + 4 * h;
            __builtin_nontemporal_store(
                __expf(acc0[r] + xsq_l[rl] + mbA),
                obA + (size_t)(m0 + rl) * UNITS);
            __builtin_nontemporal_store(
                __expf(acc1[r] + xsq_l[32 + rl] + mbA),
                obA + (size_t)(m0 + 32 + rl) * UNITS);
        }
    }

    // ---- Pass-1 epilogue (R10 shape) ----
#pragma unroll
    for (int r = 0; r < 16; r++) {
        const int rl = (r & 3) + 8 * (r >> 2) + 4 * h;
        __builtin_nontemporal_store(
            __expf(acc2[r] + xsq_l[rl] + mbB),
            obB + (size_t)(m0 + rl) * UNITS);
        __builtin_nontemporal_store(
            __expf(acc3[r] + xsq_l[32 + rl] + mbB),
            obB + (size_t)(m0 + 32 + rl) * UNITS);
    }
}

extern "C" void kernel_launch(void* const* d_in, const int* in_sizes, int n_in,
                              void* d_out, int out_size, void* d_ws, size_t ws_size,
                              hipStream_t stream) {
    const float* inputs = (const float*)d_in[0];   // [16384, 512] fp32
    const float* mu     = (const float*)d_in[1];   // [512, 1024] fp32
    float* out = (float*)d_out;                    // [16384, 1024] fp32

    char* ws = (char*)d_ws;
    unsigned char* B8f = (unsigned char*)ws;                 // 512 KiB
    float* musq = (float*)(ws + (size_t)UNITS * DIM);        // 4 KiB

    prep_b_kernel<<<32, 256, 0, stream>>>(mu, B8f, musq);
    rbf_main_kernel<<<256, 1024, 0, stream>>>(inputs, B8f, musq, out);
}

// Round 14
// 105.532 us; speedup vs baseline: 1.2708x; 1.0670x over previous
//
#include <hip/hip_runtime.h>

#define BATCH 16384
#define DIM   512
#define UNITS 1024
// GAMMA = 0.5 folded into epilogue: out = exp(cross - 0.5*xsq - 0.5*musq)

typedef float v16f __attribute__((ext_vector_type(16)));

#define MFMA_F8(a, b, c) __builtin_amdgcn_mfma_f32_32x32x16_fp8_fp8((a), (b), (c), 0, 0, 0)

static __device__ __forceinline__ int2 cvt8(const float4 f0, const float4 f1) {
    int lo = __builtin_amdgcn_cvt_pk_fp8_f32(f0.x, f0.y, 0, false);
    lo     = __builtin_amdgcn_cvt_pk_fp8_f32(f0.z, f0.w, lo, true);
    int hi = __builtin_amdgcn_cvt_pk_fp8_f32(f1.x, f1.y, 0, false);
    hi     = __builtin_amdgcn_cvt_pk_fp8_f32(f1.z, f1.w, hi, true);
    return make_int2(lo, hi);
}
static __device__ __forceinline__ float dot8(const float4 f0, const float4 f1) {
    return f0.x * f0.x + f0.y * f0.y + f0.z * f0.z + f0.w * f0.w
         + f1.x * f1.x + f1.y * f1.y + f1.z * f1.z + f1.w * f1.w;
}

// prep-B v2: split 4x along k -> 128 blocks x 256 threads (was 32 blocks).
// Block (nb = b>>2, q = b&3) handles cols [nb*32,+32) x k [q*128,+128) and
// writes B8f kws [q*8,+8) — disjoint ranges, fragment layout unchanged:
// B8f byte ((nb*32 + kw)*64 + lane)*8 holds B[kw*16+(l>>5)*8+i][nb*32+(l&31)].
// musq becomes 4 partial planes musq_p[q][1024]; main epilogue sums them.
// Per-block serial k-chain drops 4x (the kernel is latency-bound).
__global__ __launch_bounds__(256)
void prep_b_kernel(const float* __restrict__ mu, unsigned char* __restrict__ B8f,
                   float* __restrict__ musq_p) {
    __shared__ __attribute__((aligned(16))) char smem[128 * 33 * 4 + 1024];
    float* lds = (float*)smem;                       // [128][33]
    float* red = (float*)(smem + 128 * 33 * 4);      // [32][8]
    const int t  = threadIdx.x;
    const int l  = t & 63, w = t >> 6;               // wave 0..3
    const int ln = l & 31, h = l >> 5;
    const int nb = blockIdx.x >> 2;                  // col group 0..31
    const int q  = blockIdx.x & 3;                   // k-quarter 0..3
    const int n0 = nb * 32;
    const int k0 = q * 128;
    const int col = t & 31, kg = t >> 5;             // kg 0..7
    float s = 0.f;
#pragma unroll 4
    for (int i = 0; i < 16; i++) {
        const int k = i * 8 + kg;                    // 0..127
        float v = mu[(size_t)(k0 + k) * UNITS + n0 + col];
        s += v * v;
        lds[k * 33 + col] = v;
    }
    red[col * 8 + kg] = s;
    __syncthreads();
    if (t < 32) {
        float a = 0.f;
#pragma unroll
        for (int i = 0; i < 8; i++) a += red[t * 8 + i];
        musq_p[q * UNITS + n0 + t] = a;              // partial plane q
    }
#pragma unroll
    for (int j = 0; j < 2; j++) {
        const int kwl = w * 2 + j;                   // local kw 0..7
        const float* p = lds + (kwl * 16 + h * 8) * 33 + ln;
        float f[8];
#pragma unroll
        for (int i = 0; i < 8; i++) f[i] = p[i * 33];
        *(int2*)(B8f + (((size_t)nb * 32 + q * 8 + kwl) * 64 + l) * 8) =
            cvt8(make_float4(f[0], f[1], f[2], f[3]),
                 make_float4(f[4], f[5], f[6], f[7]));
    }
}

// Main RBF kernel: R10 VERBATIM (validated best: 256 blocks x 1024 threads,
// 16 waves, 1 block/CU, block-private 64 A-rows staged via coalesced-load ->
// LDS[32][516] transpose -> fp8 Afrag; wave tile 64M x 64N as two 64M x 32N
// passes, 1 global B-load per 2 MFMAs under unroll 8, per-pass epilogue).
// ONLY change: musq read sums the 4 prep-B partial planes.
__global__ __launch_bounds__(1024, 4)
void rbf_main_kernel(const float* __restrict__ in,
                     const unsigned char* __restrict__ B8f,
                     const float* __restrict__ musq_p,
                     float* __restrict__ out) {
    // LDS: stage 66048 | Afrag 32768 | red 8448 | xsq_l 256  = 107520 B
    __shared__ __attribute__((aligned(16))) unsigned char smem[107520];
    float* stage = (float*)smem;                         // [32][516] fp32
    unsigned char* Afrag = smem + 66048;                 // [2][32 kw][64 l][8]
    float* red   = (float*)(smem + 98816);               // [64][33]
    float* xsq_l = (float*)(smem + 107264);              // [64]

    const int t  = threadIdx.x;
    const int l  = t & 63;
    const int w  = t >> 6;          // wave 0..15 = 64-col group
    const int ln = l & 31;
    const int h  = l >> 5;
    const int m0 = blockIdx.x * 64; // this block's 64 A-rows

    // ---- Stage + convert two 32-row chunks (identical to R10) ----
#pragma unroll
    for (int rc = 0; rc < 2; rc++) {
        const float4* src = (const float4*)(in + (size_t)(m0 + rc * 32) * DIM);
        float4* s4 = (float4*)stage;
#pragma unroll
        for (int i = 0; i < 4; i++) {
            const int f = i * 1024 + t;                  // float4 id 0..4095
            s4[(f >> 7) * 129 + (f & 127)] = src[f];
        }
        __syncthreads();
        // convert: thread covers (row ln, k-half h) x kw = {w*2, w*2+1}
        float s = 0.f;
#pragma unroll
        for (int j = 0; j < 2; j++) {
            const int kw = w * 2 + j;
            const float* p = stage + ln * 516 + kw * 16 + h * 8;
            float4 f0 = *(const float4*)p;
            float4 f1 = *(const float4*)(p + 4);
            s += dot8(f0, f1);
            *(int2*)(Afrag + (((rc * 32 + kw) * 64) + h * 32 + ln) * 8) =
                cvt8(f0, f1);
        }
        red[(rc * 32 + ln) * 33 + w * 2 + h] = s;
        __syncthreads();
    }
    if (t < 64) {                   // xsq for all 64 rows, stays in LDS
        float a = 0.f;
#pragma unroll
        for (int i = 0; i < 32; i++) a += red[t * 33 + i];
        xsq_l[t] = -0.5f * a;
    }
    __syncthreads();                // last barrier; waves free-run from here

    // ---- Per-wave GEMM: rows [m0,+64) x cols [w*64,+64), 2 N-passes ----
    const long* Af0 = (const long*)Afrag;                // row chunk 0
    const long* Af1 = (const long*)(Afrag + 16384);      // row chunk 1
    const long* Bg  = (const long*)B8f + (size_t)(w * 2) * 2048 + l;

#pragma unroll
    for (int g2 = 0; g2 < 2; g2++) {                     // two 32-col passes
        const long* B0 = Bg + (size_t)g2 * 2048;

        v16f acc0 = (v16f)0.f, acc1 = (v16f)0.f;
#pragma unroll 8
        for (int kw = 0; kw < 32; kw++) {
            long a0 = Af0[kw * 64 + l];
            long a1 = Af1[kw * 64 + l];
            long b  = B0[kw * 64];
            acc0 = MFMA_F8(a0, b, acc0);                 // rows m0..m0+31
            acc1 = MFMA_F8(a1, b, acc1);                 // rows m0+32..m0+63
        }

        // Epilogue. C/D layout: col = l&31, row = (r&3) + 8*(r>>2) + 4*h.
        const int nc0 = w * 64 + g2 * 32;
        const float mb = -0.5f * (musq_p[nc0 + ln] + musq_p[UNITS + nc0 + ln]
                                + musq_p[2 * UNITS + nc0 + ln]
                                + musq_p[3 * UNITS + nc0 + ln]);
        float* obase = out + nc0 + ln;
#pragma unroll
        for (int r = 0; r < 16; r++) {
            const int rl = (r & 3) + 8 * (r >> 2) + 4 * h;
            const float xb0 = xsq_l[rl];                 // LDS broadcast
            const float xb1 = xsq_l[32 + rl];
            __builtin_nontemporal_store(
                __expf(acc0[r] + xb0 + mb), obase + (size_t)(m0 + rl) * UNITS);
            __builtin_nontemporal_store(
                __expf(acc1[r] + xb1 + mb), obase + (size_t)(m0 + 32 + rl) * UNITS);
        }
    }
}

extern "C" void kernel_launch(void* const* d_in, const int* in_sizes, int n_in,
                              void* d_out, int out_size, void* d_ws, size_t ws_size,
                              hipStream_t stream) {
    const float* inputs = (const float*)d_in[0];   // [16384, 512] fp32
    const float* mu     = (const float*)d_in[1];   // [512, 1024] fp32
    float* out = (float*)d_out;                    // [16384, 1024] fp32

    char* ws = (char*)d_ws;
    unsigned char* B8f = (unsigned char*)ws;                 // 512 KiB
    float* musq_p = (float*)(ws + (size_t)UNITS * DIM);      // 16 KiB (4 planes)

    prep_b_kernel<<<128, 256, 0, stream>>>(mu, B8f, musq_p);
    rbf_main_kernel<<<256, 1024, 0, stream>>>(inputs, B8f, musq_p, out);
}

// Round 15
// 104.596 us; speedup vs baseline: 1.2821x; 1.0089x over previous
//
#include <hip/hip_runtime.h>

#define BATCH 16384
#define DIM   512
#define UNITS 1024
// GAMMA = 0.5 folded into epilogue: out = exp(cross - 0.5*xsq - 0.5*musq)

typedef float v16f __attribute__((ext_vector_type(16)));

#define MFMA_F8(a, b, c) __builtin_amdgcn_mfma_f32_32x32x16_fp8_fp8((a), (b), (c), 0, 0, 0)

__device__ __forceinline__ void async_copy16(const void* g, void* l) {
    __builtin_amdgcn_global_load_lds(
        (const __attribute__((address_space(1))) void*)g,
        (__attribute__((address_space(3))) void*)l,
        16 /*bytes*/, 0 /*offset*/, 0 /*aux*/);
}

static __device__ __forceinline__ int2 cvt8(const float4 f0, const float4 f1) {
    int lo = __builtin_amdgcn_cvt_pk_fp8_f32(f0.x, f0.y, 0, false);
    lo     = __builtin_amdgcn_cvt_pk_fp8_f32(f0.z, f0.w, lo, true);
    int hi = __builtin_amdgcn_cvt_pk_fp8_f32(f1.x, f1.y, 0, false);
    hi     = __builtin_amdgcn_cvt_pk_fp8_f32(f1.z, f1.w, hi, true);
    return make_int2(lo, hi);
}
static __device__ __forceinline__ float dot8(const float4 f0, const float4 f1) {
    return f0.x * f0.x + f0.y * f0.y + f0.z * f0.z + f0.w * f0.w
         + f1.x * f1.x + f1.y * f1.y + f1.z * f1.z + f1.w * f1.w;
}

// prep-B v2 (R14, 4x k-split): 128 blocks x 256 threads. Block (nb=b>>2,
// q=b&3) covers cols [nb*32,+32) x k [q*128,+128), writes B8f kws [q*8,+8).
// B8f byte ((nb*32 + kw)*64 + lane)*8 holds B[kw*16+(l>>5)*8+i][nb*32+(l&31)].
// musq as 4 partial planes musq_p[q][1024]; main epilogue sums them.
__global__ __launch_bounds__(256)
void prep_b_kernel(const float* __restrict__ mu, unsigned char* __restrict__ B8f,
                   float* __restrict__ musq_p) {
    __shared__ __attribute__((aligned(16))) char smem[128 * 33 * 4 + 1024];
    float* lds = (float*)smem;                       // [128][33]
    float* red = (float*)(smem + 128 * 33 * 4);      // [32][8]
    const int t  = threadIdx.x;
    const int l  = t & 63, w = t >> 6;               // wave 0..3
    const int ln = l & 31, h = l >> 5;
    const int nb = blockIdx.x >> 2;                  // col group 0..31
    const int q  = blockIdx.x & 3;                   // k-quarter 0..3
    const int n0 = nb * 32;
    const int k0 = q * 128;
    const int col = t & 31, kg = t >> 5;             // kg 0..7
    float s = 0.f;
#pragma unroll 4
    for (int i = 0; i < 16; i++) {
        const int k = i * 8 + kg;                    // 0..127
        float v = mu[(size_t)(k0 + k) * UNITS + n0 + col];
        s += v * v;
        lds[k * 33 + col] = v;
    }
    red[col * 8 + kg] = s;
    __syncthreads();
    if (t < 32) {
        float a = 0.f;
#pragma unroll
        for (int i = 0; i < 8; i++) a += red[t * 8 + i];
        musq_p[q * UNITS + n0 + t] = a;              // partial plane q
    }
#pragma unroll
    for (int j = 0; j < 2; j++) {
        const int kwl = w * 2 + j;                   // local kw 0..7
        const float* p = lds + (kwl * 16 + h * 8) * 33 + ln;
        float f[8];
#pragma unroll
        for (int i = 0; i < 8; i++) f[i] = p[i * 33];
        *(int2*)(B8f + (((size_t)nb * 32 + q * 8 + kwl) * 64 + l) * 8) =
            cvt8(make_float4(f[0], f[1], f[2], f[3]),
                 make_float4(f[4], f[5], f[6], f[7]));
    }
}

// Main RBF kernel v7: R10/R14 (validated best) with ONE change: the A-staging
// global->VGPR->LDS round-trip is replaced by async global_load_lds width=16
// (direct-to-LDS DMA, no VGPR/VALU staging overhead). Dest decomposes as
// wave-uniform base + lane*16 (f>>7 and (w&1)*64 are wave-uniform), matching
// the HW's linear write pattern; the barrier's implicit vmcnt(0) drains the
// copies before the transpose reads. K-loop/epilogue byte-identical to R10.
__global__ __launch_bounds__(1024, 4)
void rbf_main_kernel(const float* __restrict__ in,
                     const unsigned char* __restrict__ B8f,
                     const float* __restrict__ musq_p,
                     float* __restrict__ out) {
    // LDS: stage 66048 | Afrag 32768 | red 8448 | xsq_l 256  = 107520 B
    __shared__ __attribute__((aligned(16))) unsigned char smem[107520];
    float* stage = (float*)smem;                         // [32][516] fp32
    unsigned char* Afrag = smem + 66048;                 // [2][32 kw][64 l][8]
    float* red   = (float*)(smem + 98816);               // [64][33]
    float* xsq_l = (float*)(smem + 107264);              // [64]

    const int t  = threadIdx.x;
    const int l  = t & 63;
    const int w  = t >> 6;          // wave 0..15 = 64-col group
    const int ln = l & 31;
    const int h  = l >> 5;
    const int m0 = blockIdx.x * 64; // this block's 64 A-rows

    // ---- Stage + convert two 32-row chunks (async direct-to-LDS) ----
#pragma unroll
    for (int rc = 0; rc < 2; rc++) {
        const float4* src = (const float4*)(in + (size_t)(m0 + rc * 32) * DIM);
#pragma unroll
        for (int i = 0; i < 4; i++) {
            const int f = i * 1024 + t;                  // float4 id 0..4095
            async_copy16(src + f,
                         (char*)stage + ((f >> 7) * 129 + (f & 127)) * 16);
        }
        __syncthreads();                                 // drains vmcnt(0)
        // convert: thread covers (row ln, k-half h) x kw = {w*2, w*2+1}
        float s = 0.f;
#pragma unroll
        for (int j = 0; j < 2; j++) {
            const int kw = w * 2 + j;
            const float* p = stage + ln * 516 + kw * 16 + h * 8;
            float4 f0 = *(const float4*)p;
            float4 f1 = *(const float4*)(p + 4);
            s += dot8(f0, f1);
            *(int2*)(Afrag + (((rc * 32 + kw) * 64) + h * 32 + ln) * 8) =
                cvt8(f0, f1);
        }
        red[(rc * 32 + ln) * 33 + w * 2 + h] = s;
        __syncthreads();
    }
    if (t < 64) {                   // xsq for all 64 rows, stays in LDS
        float a = 0.f;
#pragma unroll
        for (int i = 0; i < 32; i++) a += red[t * 33 + i];
        xsq_l[t] = -0.5f * a;
    }
    __syncthreads();                // last barrier; waves free-run from here

    // ---- Per-wave GEMM: rows [m0,+64) x cols [w*64,+64), 2 N-passes ----
    const long* Af0 = (const long*)Afrag;                // row chunk 0
    const long* Af1 = (const long*)(Afrag + 16384);      // row chunk 1
    const long* Bg  = (const long*)B8f + (size_t)(w * 2) * 2048 + l;

#pragma unroll
    for (int g2 = 0; g2 < 2; g2++) {                     // two 32-col passes
        const long* B0 = Bg + (size_t)g2 * 2048;

        v16f acc0 = (v16f)0.f, acc1 = (v16f)0.f;
#pragma unroll 8
        for (int kw = 0; kw < 32; kw++) {
            long a0 = Af0[kw * 64 + l];
            long a1 = Af1[kw * 64 + l];
            long b  = B0[kw * 64];
            acc0 = MFMA_F8(a0, b, acc0);                 // rows m0..m0+31
            acc1 = MFMA_F8(a1, b, acc1);                 // rows m0+32..m0+63
        }

        // Epilogue. C/D layout: col = l&31, row = (r&3) + 8*(r>>2) + 4*h.
        const int nc0 = w * 64 + g2 * 32;
        const float mb = -0.5f * (musq_p[nc0 + ln] + musq_p[UNITS + nc0 + ln]
                                + musq_p[2 * UNITS + nc0 + ln]
                                + musq_p[3 * UNITS + nc0 + ln]);
        float* obase = out + nc0 + ln;
#pragma unroll
        for (int r = 0; r < 16; r++) {
            const int rl = (r & 3) + 8 * (r >> 2) + 4 * h;
            const float xb0 = xsq_l[rl];                 // LDS broadcast
            const float xb1 = xsq_l[32 + rl];
            __builtin_nontemporal_store(
                __expf(acc0[r] + xb0 + mb), obase + (size_t)(m0 + rl) * UNITS);
            __builtin_nontemporal_store(
                __expf(acc1[r] + xb1 + mb), obase + (size_t)(m0 + 32 + rl) * UNITS);
        }
    }
}

extern "C" void kernel_launch(void* const* d_in, const int* in_sizes, int n_in,
                              void* d_out, int out_size, void* d_ws, size_t ws_size,
                              hipStream_t stream) {
    const float* inputs = (const float*)d_in[0];   // [16384, 512] fp32
    const float* mu     = (const float*)d_in[1];   // [512, 1024] fp32
    float* out = (float*)d_out;                    // [16384, 1024] fp32

    char* ws = (char*)d_ws;
    unsigned char* B8f = (unsigned char*)ws;                 // 512 KiB
    float* musq_p = (float*)(ws + (size_t)UNITS * DIM);      // 16 KiB (4 planes)

    prep_b_kernel<<<128, 256, 0, stream>>>(mu, B8f, musq_p);
    rbf_main_kernel<<<256, 1024, 0, stream>>>(inputs, B8f, musq_p, out);
}